// Round 12
// baseline (38.582 us; speedup 1.0000x reference)
//
#include <hip/hip_runtime.h>
#include <math.h>

// MotionBlur: out = p0*Vtop + p1*Vbot + p3*Hleft + p2*Hright (8-tap box sums).
// x: [64,1,512,512] f32; logits,gumbel: [1,4] f32; out: [64,1,512,512] f32.
//
// Full-row wave structure: each lane owns 8 contiguous cols (64 lanes x 8 =
// 512 = whole row), each wave streams 8 rows. No column tiles -> no horizontal
// halo loads; image edges are zero-predications on lanes 0/63. Horizontal
// 16-tap from own prefix + one neighbor-lane shuffle each side (16 bpermutes
// per 512 px). Vertical 16-tap via 16-deep register FIFO + rolling VA/VB.
// ~200 VGPR -> 2 waves/SIMD; latency hidden by 4-deep load pipeline (ILP).

#define IMG   512
#define IMG4  128   // float4s per row

typedef float nfloat4 __attribute__((ext_vector_type(4)));

static __device__ __forceinline__ float4 f4z() {
    return make_float4(0.f, 0.f, 0.f, 0.f);
}

static __device__ __forceinline__ void load_row8(
    const float4* __restrict__ xi4, int r, int lane, float dst[8])
{
    float4 a = f4z(), b = f4z();
    if ((unsigned)r < (unsigned)IMG) {
        a = xi4[r * IMG4 + 2 * lane];
        b = xi4[r * IMG4 + 2 * lane + 1];
    }
    dst[0] = a.x; dst[1] = a.y; dst[2] = a.z; dst[3] = a.w;
    dst[4] = b.x; dst[5] = b.y; dst[6] = b.z; dst[7] = b.w;
}

__global__ __launch_bounds__(256, 2) void motion_blur_kernel(
    const float* __restrict__ x,
    const float* __restrict__ logits,
    const float* __restrict__ gnoise,
    float* __restrict__ out)
{
    const int t    = threadIdx.x;
    const int lane = t & 63;
    const int wv   = t >> 6;

    // XCD-chunk swizzle: 1024 blocks, 8 XCDs -> 128 contiguous logical per XCD
    const int bid  = blockIdx.x;
    const int lbid = (bid & 7) * 128 + (bid >> 3);

    const int img = lbid >> 4;          // 16 blocks per image (32 rows each)
    const int y0  = (lbid & 15) * 32 + wv * 8;

    // gumbel-softmax probs (tau=1): softmax(logits + noise)
    float l0 = logits[0] + gnoise[0];
    float l1 = logits[1] + gnoise[1];
    float l2 = logits[2] + gnoise[2];
    float l3 = logits[3] + gnoise[3];
    float mx = fmaxf(fmaxf(l0, l1), fmaxf(l2, l3));
    float e0 = expf(l0 - mx), e1 = expf(l1 - mx);
    float e2 = expf(l2 - mx), e3 = expf(l3 - mx);
    float inv = 1.0f / (e0 + e1 + e2 + e3);
    const float p0 = e0 * inv;   // north: rows y-7..y
    const float p1 = e1 * inv;   // south: rows y+1..y+8
    const float p2 = e2 * inv;   // east:  cols x+1..x+8
    const float p3 = e3 * inv;   // west:  cols x-7..x

    const float4* __restrict__ xi4 =
        reinterpret_cast<const float4*>(x) + (size_t)img * (IMG * IMG4);

    const int lm1 = (lane - 1) & 63;
    const int lp1 = (lane + 1) & 63;

    // ---- warm-up: rows y0-7 .. y0+8 into FIFO slot (row - y0) & 15 ----
    float fifo[16][8];
    #pragma unroll
    for (int k = 0; k < 16; ++k)
        load_row8(xi4, y0 - 7 + k, lane, fifo[(9 + k) & 15]);

    float VA[8], VB[8];
    #pragma unroll
    for (int j = 0; j < 8; ++j) { VA[j] = 0.f; VB[j] = 0.f; }
    #pragma unroll
    for (int k = 0; k < 8; ++k) {        // rows y0-7..y0 -> slots 9..15,0
        #pragma unroll
        for (int j = 0; j < 8; ++j) VA[j] += fifo[(9 + k) & 15][j];
    }
    #pragma unroll
    for (int k = 0; k < 8; ++k) {        // rows y0+1..y0+8 -> slots 1..8
        #pragma unroll
        for (int j = 0; j < 8; ++j) VB[j] += fifo[(1 + k) & 15][j];
    }

    // ---- 4-deep load pipeline: rows y0+9..y0+12 ----
    float pre[4][8];
    #pragma unroll
    for (int k = 0; k < 4; ++k)
        load_row8(xi4, y0 + 9 + k, lane, pre[k]);

    float* __restrict__ obase =
        out + (size_t)img * (IMG * IMG) + (size_t)y0 * IMG + lane * 8;

    #pragma unroll
    for (int i = 0; i < 8; ++i) {
        // keep VMEM in program order across iterations (reg-pressure control)
        __builtin_amdgcn_sched_barrier(0x7);

        // intra-lane inclusive prefix over this row's 8 cols
        float L[8];
        L[0] = fifo[i & 15][0];
        #pragma unroll
        for (int j = 1; j < 8; ++j) L[j] = L[j - 1] + fifo[i & 15][j];

        // neighbor prefixes (one lane each side)
        float Lm[8], Lp[8];
        #pragma unroll
        for (int j = 0; j < 8; ++j) {
            Lm[j] = __shfl(L[j], lm1);
            Lp[j] = __shfl(L[j], lp1);
        }
        if (lane == 0) {
            #pragma unroll
            for (int j = 0; j < 8; ++j) Lm[j] = 0.f;   // cols < 0 are zero
        }
        if (lane == 63) {
            #pragma unroll
            for (int j = 0; j < 8; ++j) Lp[j] = 0.f;   // cols >= 512 are zero
        }
        const float Sm = Lm[7];    // sum of left-neighbor group
        const float S  = L[7];     // sum of own group

        // W_j = cols c-7..c = (Sm - Lm_j) + L_j ; E_j = (S - L_j) + Lp_j
        float res[8];
        #pragma unroll
        for (int j = 0; j < 8; ++j) {
            const float W = (Sm - Lm[j]) + L[j];
            const float E = (S - L[j]) + Lp[j];
            res[j] = fmaf(p0, VA[j], fmaf(p1, VB[j], fmaf(p3, W, p2 * E)));
        }
        nfloat4 r0 = {res[0], res[1], res[2], res[3]};
        nfloat4 r1 = {res[4], res[5], res[6], res[7]};
        float* orow = obase + (size_t)i * IMG;
        __builtin_nontemporal_store(r0, reinterpret_cast<nfloat4*>(orow));
        __builtin_nontemporal_store(r1, reinterpret_cast<nfloat4*>(orow) + 1);

        if (i < 7) {
            // step vertical window y -> y+1
            #pragma unroll
            for (int j = 0; j < 8; ++j) {
                const float a = fifo[(i + 1) & 15][j];   // row y+1
                const float b = fifo[(i + 9) & 15][j];   // row y-7 (leaving)
                const float n = pre[i & 3][j];           // row y+9
                VA[j] += a - b;
                VB[j] += n - a;
            }
            #pragma unroll
            for (int j = 0; j < 8; ++j) fifo[(i + 9) & 15][j] = pre[i & 3][j];
            if (i <= 2)                                   // refill rows y0+13..15
                load_row8(xi4, y0 + 13 + i, lane, pre[i & 3]);
        }
    }
}

extern "C" void kernel_launch(void* const* d_in, const int* in_sizes, int n_in,
                              void* d_out, int out_size, void* d_ws, size_t ws_size,
                              hipStream_t stream) {
    const float* x      = (const float*)d_in[0];
    const float* logits = (const float*)d_in[1];
    const float* gn     = (const float*)d_in[2];
    float* outp         = (float*)d_out;
    // 64 images x 16 row-blocks (32 rows) = 1024 blocks of 4 waves;
    // each wave owns an 8-row x 512-col (full-width) band.
    motion_blur_kernel<<<dim3(1024), dim3(256), 0, stream>>>(x, logits, gn, outp);
}

// Round 13
// 31.893 us; speedup vs baseline: 1.2097x; 1.2097x over previous
//
#include <hip/hip_runtime.h>
#include <math.h>

// MotionBlur: out = p0*Vtop + p1*Vbot + p3*Hleft + p2*Hright (8-tap box sums).
// x: [64,1,512,512] f32; logits,gumbel: [1,4] f32; out: [64,1,512,512] f32.
//
// R10 structure (best: 32.3us) with two deltas:
//  - 1-wave blocks (64 threads x 8192 blocks): finer scheduling granularity,
//    smoother CU fill/drain than 4-wave blocks.
//  - plain float4 stores (no nontemporal hint): use the same write path
//    fillBuffer saturates at 6.7 TB/s on this machine.
// Wave = 256 cols (64 lanes x float4) x 8 rows. Vertical 16-tap via 16-deep
// register FIFO + rolling VA/VB box sums; horizontal 16-tap via intra-lane
// prefix + cross-lane shuffles; 4 edge lanes fetch the 8-col halo (L2-hot).

#define IMG   512
#define IMG4  128   // float4s per row

static __device__ __forceinline__ float4 f4z() {
    return make_float4(0.f, 0.f, 0.f, 0.f);
}

__global__ __launch_bounds__(64, 4) void motion_blur_kernel(
    const float* __restrict__ x,
    const float* __restrict__ logits,
    const float* __restrict__ gnoise,
    float* __restrict__ out)
{
    const int lane = threadIdx.x & 63;

    // XCD-chunk swizzle: 8192 blocks, 8 XCDs -> 1024 contiguous logical per
    // XCD (= 8 whole images per XCD; halo re-reads stay in that L2).
    const int bid  = blockIdx.x;
    const int lbid = (bid & 7) * 1024 + (bid >> 3);

    const int img  = lbid >> 7;        // 128 blocks per image
    const int rem  = lbid & 127;
    const int ct   = rem >> 6;         // column tile 0/1 (256 cols each)
    const int y0   = (rem & 63) * 8;   // 8-row band
    const int c4t  = ct * 64;          // tile base in float4 units
    const int c4   = c4t + lane;       // this lane's float4 column block

    // gumbel-softmax probs (tau=1): softmax(logits + noise)
    float l0 = logits[0] + gnoise[0];
    float l1 = logits[1] + gnoise[1];
    float l2 = logits[2] + gnoise[2];
    float l3 = logits[3] + gnoise[3];
    float mx = fmaxf(fmaxf(l0, l1), fmaxf(l2, l3));
    float e0 = expf(l0 - mx), e1 = expf(l1 - mx);
    float e2 = expf(l2 - mx), e3 = expf(l3 - mx);
    float inv = 1.0f / (e0 + e1 + e2 + e3);
    const float p0  = e0 * inv;   // north: rows y-7..y
    const float p1  = e1 * inv;   // south: rows y+1..y+8
    const float p2  = e2 * inv;   // east:  cols x+1..x+8
    const float p3  = e3 * inv;   // west:  cols x-7..x
    const float q32 = p3 - p2;
    const float np3 = -p3;

    const float4* __restrict__ xi4 =
        reinterpret_cast<const float4*>(x) + (size_t)img * (IMG * IMG4);

    // Horizontal halo: lane 0 -> block -2, lane 1 -> block -1,
    // lane 62 -> block +64, lane 63 -> block +65 (relative to tile base).
    const int  hc4   = c4t + ((lane < 2) ? (lane - 2) : (lane + 2));
    const bool hlane = (lane < 2) || (lane >= 62);
    const bool hok   = hlane && ((unsigned)hc4 < (unsigned)IMG4);

    const int lm2 = (lane - 2) & 63;
    const int lm1 = (lane - 1) & 63;
    const int lp1 = (lane + 1) & 63;
    const int lp2 = (lane + 2) & 63;

    // ---- warm-up: rows y0-7 .. y0+8 into FIFO slot (row - y0) & 15 ----
    float4 fifo[16];
    #pragma unroll
    for (int k = 0; k < 16; ++k) {
        const int r = y0 - 7 + k;
        float4 v = f4z();
        if ((unsigned)r < (unsigned)IMG) v = xi4[r * IMG4 + c4];
        fifo[(9 + k) & 15] = v;
    }
    float4 VA = f4z(), VB = f4z();
    #pragma unroll
    for (int k = 0; k < 8; ++k) {   // rows y0-7..y0 -> slots 9..15,0
        const float4 v = fifo[(9 + k) & 15];
        VA.x += v.x; VA.y += v.y; VA.z += v.z; VA.w += v.w;
    }
    #pragma unroll
    for (int k = 0; k < 8; ++k) {   // rows y0+1..y0+8 -> slots 1..8
        const float4 v = fifo[(1 + k) & 15];
        VB.x += v.x; VB.y += v.y; VB.z += v.z; VB.w += v.w;
    }

    // ---- 4-deep main-load pipeline: rows y0+9..y0+12 ----
    float4 pre[4];
    #pragma unroll
    for (int k = 0; k < 4; ++k) {
        const int r = y0 + 9 + k;
        float4 v = f4z();
        if (r < IMG) v = xi4[r * IMG4 + c4];
        pre[k] = v;
    }

    // ---- halo prefetch for first output row ----
    float4 hv_cur = f4z();
    if (hok) hv_cur = xi4[y0 * IMG4 + hc4];

    float* __restrict__ obase =
        out + (size_t)img * (IMG * IMG) + (size_t)y0 * IMG + 4 * c4;

    #pragma unroll
    for (int i = 0; i < 8; ++i) {
        // keep VMEM in program order across iterations (reg-pressure control);
        // ALU may cross (mask 0x7 = ALU|VALU|SALU).
        __builtin_amdgcn_sched_barrier(0x7);

        // halo prefetch for next output row (1-iter slack before use)
        float4 hv_next = f4z();
        if (i < 7 && hok) hv_next = xi4[(y0 + i + 1) * IMG4 + hc4];

        const float4 cur = fifo[i & 15];
        // intra-block inclusive prefix
        const float L0 = cur.x;
        const float L1 = L0 + cur.y;
        const float L2 = L1 + cur.z;
        const float L3 = L2 + cur.w;
        const float hL0 = hv_cur.x;
        const float hL1 = hL0 + hv_cur.y;
        const float hL2 = hL1 + hv_cur.z;
        const float hL3 = hL2 + hv_cur.w;

        // L of block x-2 (west halo via own halo regs on lanes 0,1)
        float Lm0 = __shfl(L0, lm2), Lm1 = __shfl(L1, lm2),
              Lm2_ = __shfl(L2, lm2), Lm3 = __shfl(L3, lm2);
        if (lane < 2) { Lm0 = hL0; Lm1 = hL1; Lm2_ = hL2; Lm3 = hL3; }
        // L of block x+2 (east halo on lanes 62,63)
        float Lp0 = __shfl(L0, lp2), Lp1 = __shfl(L1, lp2),
              Lp2_ = __shfl(L2, lp2), Lp3 = __shfl(L3, lp2);
        if (lane >= 62) { Lp0 = hL0; Lp1 = hL1; Lp2_ = hL2; Lp3 = hL3; }
        // block sums of x-1 / x+1
        float sm1 = __shfl(L3, lm1);
        const float sm1h = __shfl(hL3, 1);    // lane 1's halo = block -1
        if (lane == 0) sm1 = sm1h;
        float sp1 = __shfl(L3, lp1);
        const float sp1h = __shfl(hL3, 62);   // lane 62's halo = block +64
        if (lane == 63) sp1 = sp1h;

        // W_i = (Lm3 + sm1) + L_i - Lm_i ; E_i = (L3 + sp1) + Lp_i - L_i
        const float base = p3 * (Lm3 + sm1) + p2 * (L3 + sp1);
        float4 r4;
        r4.x = fmaf(p0, VA.x, fmaf(p1, VB.x,
                 fmaf(q32, L0, fmaf(np3, Lm0, fmaf(p2, Lp0, base)))));
        r4.y = fmaf(p0, VA.y, fmaf(p1, VB.y,
                 fmaf(q32, L1, fmaf(np3, Lm1, fmaf(p2, Lp1, base)))));
        r4.z = fmaf(p0, VA.z, fmaf(p1, VB.z,
                 fmaf(q32, L2, fmaf(np3, Lm2_, fmaf(p2, Lp2_, base)))));
        r4.w = fmaf(p0, VA.w, fmaf(p1, VB.w,
                 fmaf(q32, L3, fmaf(np3, Lm3, fmaf(p2, Lp3, base)))));
        *reinterpret_cast<float4*>(obase + (size_t)i * IMG) = r4;

        if (i < 7) {
            // step vertical window y -> y+1
            const float4 vnew = pre[i & 3];            // row y+9
            const float4 a = fifo[(i + 1) & 15];       // row y+1
            const float4 b = fifo[(i + 9) & 15];       // row y-7 (leaving)
            VA.x += a.x - b.x; VA.y += a.y - b.y;
            VA.z += a.z - b.z; VA.w += a.w - b.w;
            VB.x += vnew.x - a.x; VB.y += vnew.y - a.y;
            VB.z += vnew.z - a.z; VB.w += vnew.w - a.w;
            fifo[(i + 9) & 15] = vnew;
            if (i <= 2) {                              // refill rows y0+13..15
                const int r = y0 + 13 + i;
                float4 v = f4z();
                if (r < IMG) v = xi4[r * IMG4 + c4];
                pre[i & 3] = v;
            }
        }
        hv_cur = hv_next;
    }
}

extern "C" void kernel_launch(void* const* d_in, const int* in_sizes, int n_in,
                              void* d_out, int out_size, void* d_ws, size_t ws_size,
                              hipStream_t stream) {
    const float* x      = (const float*)d_in[0];
    const float* logits = (const float*)d_in[1];
    const float* gn     = (const float*)d_in[2];
    float* outp         = (float*)d_out;
    // 64 images x 2 column tiles x 64 row-bands = 8192 single-wave blocks
    motion_blur_kernel<<<dim3(8192), dim3(64), 0, stream>>>(x, logits, gn, outp);
}